// Round 8
// baseline (504.465 us; speedup 1.0000x reference)
//
#include <hip/hip_runtime.h>
#include <stdint.h>

#define DEV __device__ __forceinline__

typedef __attribute__((ext_vector_type(8))) short short8;   // 8 bf16 = 4 VGPRs
typedef __attribute__((ext_vector_type(4))) float f32x4;

// ---------- helpers ----------
DEV unsigned short f2bf(float f) {
    union { float f; uint32_t u; } v; v.f = f;
    uint32_t u = v.u;
    return (unsigned short)((u + 0x7fffu + ((u >> 16) & 1u)) >> 16);  // RNE
}
DEV float silu_f(float x) { return x / (1.0f + __expf(-x)); }
DEV float softplus_f(float x) { return (x > 20.0f) ? x : log1pf(__expf(x)); }

// token row (0..4095) in fwd-token space for direction-k position l
DEV int tokx(int bk, int l) {            // bk = b*4 + k
    int b = bk >> 2;
    int nn = bk & 1;
    int lf = (bk & 2) ? (1023 - l) : l;  // k>=2 scans the flipped sequence
    return (b * 2 + nn) * 1024 + lf;
}

// degree-3 B-spline bases on uniform grid g[j] = 0.4*(j-3) - 1, j=0..11 -> 8 bases
DEV void bspline8(float x, float* bo) {
    float b[11];
#pragma unroll
    for (int j = 0; j < 11; ++j) {
        float gj  = 0.4f * (float)(j - 3) - 1.0f;
        float gj1 = 0.4f * (float)(j - 2) - 1.0f;
        b[j] = (x >= gj && x < gj1) ? 1.0f : 0.0f;
    }
#pragma unroll
    for (int k = 1; k <= 3; ++k) {
        float inv = 1.0f / (0.4f * (float)k);
#pragma unroll
        for (int j = 0; j + k < 11; ++j) {
            float gj  = 0.4f * (float)(j - 3) - 1.0f;      // g[j]
            float gk1 = 0.4f * (float)(j + k - 2) - 1.0f;  // g[j+k+1]
            b[j] = ((x - gj) * b[j] + (gk1 - x) * b[j + 1]) * inv;
        }
    }
#pragma unroll
    for (int j = 0; j < 8; ++j) bo[j] = b[j];
}

// ---------- zero fill ----------
__global__ __launch_bounds__(256) void zero_kernel(float4* __restrict__ p, int n4) {
    int i = blockIdx.x * 256 + threadIdx.x;
    if (i < n4) p[i] = make_float4(0.f, 0.f, 0.f, 0.f);
}

// ---------- dst += s1 + s2 ----------
__global__ __launch_bounds__(256) void add3_kernel(float4* __restrict__ dst,
        const float4* __restrict__ s1, const float4* __restrict__ s2, int n4) {
    int i = blockIdx.x * 256 + threadIdx.x;
    if (i >= n4) return;
    float4 d = dst[i], a = s1[i], b = s2[i];
    d.x += a.x + b.x; d.y += a.y + b.y; d.z += a.z + b.z; d.w += a.w + b.w;
    dst[i] = d;
}

// ---------- dst += s1 + s2 + s3 ----------
__global__ __launch_bounds__(256) void add4_kernel(float4* __restrict__ dst,
        const float4* __restrict__ s1, const float4* __restrict__ s2,
        const float4* __restrict__ s3, int n4) {
    int i = blockIdx.x * 256 + threadIdx.x;
    if (i >= n4) return;
    float4 d = dst[i], a = s1[i], b = s2[i], c = s3[i];
    d.x += a.x + b.x + c.x; d.y += a.y + b.y + c.y;
    d.z += a.z + b.z + c.z; d.w += a.w + b.w + c.w;
    dst[i] = d;
}

// ---------- weight fold (8 elems/thread): Wc[o, i*9+0]=bw, [i*9+1+j]=sw*sc ----------
__global__ __launch_bounds__(256) void wc8_kernel(const float* __restrict__ bw,
        const float* __restrict__ sw, const float* __restrict__ sc,
        unsigned short* __restrict__ Wc, int total) {
    int g = (blockIdx.x * 256 + threadIdx.x) * 8;
    if (g >= total) return;
    float bwv[8], scv[8], swv[64];
    *(float4*)&bwv[0] = *(const float4*)&bw[g];
    *(float4*)&bwv[4] = *(const float4*)&bw[g + 4];
    *(float4*)&scv[0] = *(const float4*)&sc[g];
    *(float4*)&scv[4] = *(const float4*)&sc[g + 4];
#pragma unroll
    for (int q = 0; q < 16; ++q) *(float4*)&swv[q * 4] = *(const float4*)&sw[(size_t)g * 8 + q * 4];
    unsigned short buf[72];
#pragma unroll
    for (int e = 0; e < 8; ++e) {
        buf[e * 9] = f2bf(bwv[e]);
#pragma unroll
        for (int j = 0; j < 8; ++j) buf[e * 9 + 1 + j] = f2bf(swv[e * 8 + j] * scv[e]);
    }
    unsigned short* o = Wc + (size_t)g * 9;
#pragma unroll
    for (int q = 0; q < 9; ++q) *(short8*)&o[q * 8] = *(short8*)&buf[q * 8];
}

// ---------- feature expansion (8 elems/thread): F[t, i*9+j] (bf16) ----------
__global__ __launch_bounds__(256) void feat8_kernel(const float* __restrict__ X,
        unsigned short* __restrict__ F, int total) {
    int g = (blockIdx.x * 256 + threadIdx.x) * 8;
    if (g >= total) return;
    float xv[8];
    *(float4*)&xv[0] = *(const float4*)&X[g];
    *(float4*)&xv[4] = *(const float4*)&X[g + 4];
    unsigned short buf[72];
#pragma unroll
    for (int e = 0; e < 8; ++e) {
        float x = xv[e];
        buf[e * 9] = f2bf(silu_f(x));
        float bo[8];
        bspline8(x, bo);
#pragma unroll
        for (int j = 0; j < 8; ++j) buf[e * 9 + 1 + j] = f2bf(bo[j]);
    }
    unsigned short* o = F + (size_t)g * 9;
#pragma unroll
    for (int q = 0; q < 9; ++q) *(short8*)&o[q * 8] = *(short8*)&buf[q * 8];
}

// ---------- MFMA GEMM, m97 structure: NB=1, 2 barriers/K-step, minimal LDS ----------
// Mechanism (m97/m114): many co-resident blocks/CU overlap each other's stage
// latency via wave-level TLP; explicit multi-buffer pipelines cost LDS and lose.
// C[M,N] (+)= A[M,K'](bf16)*B[N,K'](bf16)^T over K-chunk z; partial z -> C0..C3.
// 256 threads = 4 waves (2x2); per-wave tile (BM/2)x(BN/2); BK=32 (64B rows).
// LDS both-sides XOR swizzle (R5-verified: bank conflicts = 0).
// Bijective XCD swizzle on flattened grid (all grids %8 == 0).
template<int BM, int BN, bool ATOMIC>
__global__ __launch_bounds__(256) void gemm_mfma3(const unsigned short* __restrict__ A,
        const unsigned short* __restrict__ B, float* __restrict__ C0,
        float* __restrict__ C1, float* __restrict__ C2, float* __restrict__ C3,
        int M, int N, int K, int klen, int gx, int gy, int gz) {
    constexpr int FRM = BM / 32;
    constexpr int FRN = BN / 32;
    constexpr int GLA = (BM * 64) / 4096;
    constexpr int GLB = (BN * 64) / 4096;
    __shared__ unsigned short As[BM * 32];
    __shared__ unsigned short Bs[BN * 32];

    const int nwg = gx * gy * gz;
    int fid = (blockIdx.z * gy + blockIdx.y) * gx + blockIdx.x;
    int cpx = nwg >> 3;
    fid = (fid & 7) * cpx + (fid >> 3);
    const int bx = fid % gx;
    const int by = (fid / gx) % gy;
    const int bz = fid / (gx * gy);

    const int tid = threadIdx.x;
    const int lane = tid & 63;
    const int w = tid >> 6;
    const int wr = w >> 1, wc = w & 1;
    const int bm = bx * BM, bn = by * BN;
    const int kbase = bz * klen;
    const int NT = klen / 32;
    const int frow = lane & 15;
    const int uq = ((lane >> 4) ^ ((frow >> 1) & 3)) * 8;   // swizzled k-quarter

    float* __restrict__ C = (bz == 0) ? C0 : (bz == 1) ? C1 : (bz == 2) ? C2 : C3;

    f32x4 acc[FRM][FRN];
#pragma unroll
    for (int m = 0; m < FRM; ++m)
#pragma unroll
        for (int n = 0; n < FRN; ++n)
            acc[m][n] = (f32x4){0.f, 0.f, 0.f, 0.f};

    for (int t = 0; t < NT; ++t) {
        const int k0 = kbase + t * 32;
#pragma unroll
        for (int r = 0; r < GLA; ++r) {
            int bo = r * 4096 + tid * 16;
            int row = bo >> 6;
            int lu = ((bo >> 4) & 3) ^ ((row >> 1) & 3);
            __builtin_amdgcn_global_load_lds(
                (const __attribute__((address_space(1))) void*)((const char*)A + ((size_t)(bm + row) * K + k0) * 2 + lu * 16),
                (__attribute__((address_space(3))) void*)((char*)As + bo), 16, 0, 0);
        }
#pragma unroll
        for (int r = 0; r < GLB; ++r) {
            int bo = r * 4096 + tid * 16;
            int row = bo >> 6;
            int lu = ((bo >> 4) & 3) ^ ((row >> 1) & 3);
            __builtin_amdgcn_global_load_lds(
                (const __attribute__((address_space(1))) void*)((const char*)B + ((size_t)(bn + row) * K + k0) * 2 + lu * 16),
                (__attribute__((address_space(3))) void*)((char*)Bs + bo), 16, 0, 0);
        }
        __syncthreads();                      // drains vmcnt before reads

        short8 af[FRM], bf[FRN];
#pragma unroll
        for (int m = 0; m < FRM; ++m)
            af[m] = *(const short8*)&As[(wr * (BM / 2) + m * 16 + frow) * 32 + uq];
#pragma unroll
        for (int n = 0; n < FRN; ++n)
            bf[n] = *(const short8*)&Bs[(wc * (BN / 2) + n * 16 + frow) * 32 + uq];
#pragma unroll
        for (int m = 0; m < FRM; ++m)
#pragma unroll
            for (int n = 0; n < FRN; ++n)
                acc[m][n] = __builtin_amdgcn_mfma_f32_16x16x32_bf16(af[m], bf[n], acc[m][n], 0, 0, 0);
        __syncthreads();                      // WAR: all reads done before next stage
    }

    // C/D layout: col=lane&15, row=(lane>>4)*4+reg  [m89/m91 verified]
    const int crow = (lane >> 4) * 4;
    const int ccol = lane & 15;
#pragma unroll
    for (int m = 0; m < FRM; ++m)
#pragma unroll
        for (int n = 0; n < FRN; ++n) {
            int gr = bm + wr * (BM / 2) + m * 16 + crow;
            int gc = bn + wc * (BN / 2) + n * 16 + ccol;
#pragma unroll
            for (int r = 0; r < 4; ++r) {
                if (ATOMIC) atomicAdd(&C[(size_t)(gr + r) * N + gc], acc[m][n][r]);
                else        C[(size_t)(gr + r) * N + gc] = acc[m][n][r];
            }
        }
}

// ---------- causal depthwise conv1d + SiLU -> xs forward only (b*2+nn, l, d) ----------
__global__ __launch_bounds__(256) void conv_xs_kernel(const float* __restrict__ xz,
        const float* __restrict__ cw, const float* __restrict__ cb,
        float* __restrict__ xsb) {
    int idx = blockIdx.x * 256 + threadIdx.x;     // (bn, l, d)
    int d = idx & 511;
    int l = (idx >> 9) & 1023;
    int bn = idx >> 19;                           // 0..3 = b*2+nn
    const float* xcol = xz + (size_t)(bn * 1024) * 1024 + d;
    float acc = cb[d];
#pragma unroll
    for (int h = 0; h < 4; ++h) {
        int ls = l - 3 + h;
        float xv = (ls >= 0) ? xcol[(size_t)ls * 1024] : 0.0f;
        acc = fmaf(cw[d * 4 + h], xv, acc);
    }
    xsb[((size_t)bn * 1024 + l) * 512 + d] = silu_f(acc);
}

// ---------- dts = xdbl[:, :32] @ dt_w^T  (no bias/softplus; 4096 fwd tokens) ----------
__global__ __launch_bounds__(256) void dts_kernel(const float* __restrict__ xdbl,
        const float* __restrict__ dtw, float* __restrict__ dts) {
    int t = blockIdx.x >> 1;                 // token 0..4095
    int half = blockIdx.x & 1;
    int d = half * 256 + threadIdx.x;
    __shared__ float dtv[32];
    if (threadIdx.x < 32) dtv[threadIdx.x] = xdbl[(size_t)t * 64 + threadIdx.x];
    __syncthreads();
    const float* w = dtw + (size_t)d * 32;
    float acc = 0.0f;
#pragma unroll
    for (int r = 0; r < 32; r += 4) {
        float4 wv = *(const float4*)(w + r);
        acc = fmaf(dtv[r], wv.x, acc);
        acc = fmaf(dtv[r + 1], wv.y, acc);
        acc = fmaf(dtv[r + 2], wv.z, acc);
        acc = fmaf(dtv[r + 3], wv.w, acc);
    }
    dts[(size_t)t * 512 + d] = acc;
}

// ---------- chunked selective scan: 32 chunks x 32 steps, delta inline ----------
// phase A: per (bk,chunk,d): P = prod a, Q = h_end with h0=0
__global__ __launch_bounds__(256) void scanA_kernel(const float* __restrict__ dts,
        const float* __restrict__ xsb, const float* __restrict__ xdbl,
        const float* __restrict__ A_logs, const float* __restrict__ dtb,
        float* __restrict__ P, float* __restrict__ Q) {
    int half = blockIdx.x & 1;
    int chunk = (blockIdx.x >> 1) & 31;
    int bk = blockIdx.x >> 6;                // 0..7 = b*4+k
    int k = bk & 3;
    int d = half * 256 + threadIdx.x;
    __shared__ float Bl[32][16];
    for (int s = threadIdx.x; s < 32 * 16; s += 256) {
        int ll = s >> 4, n = s & 15;
        Bl[ll][n] = xdbl[(size_t)tokx(bk, chunk * 32 + ll) * 64 + 32 + n];
    }
    __syncthreads();
    float An[16];
#pragma unroll
    for (int n = 0; n < 16; ++n) An[n] = -__expf(A_logs[(size_t)(k * 512 + d) * 16 + n]);
    float bias = dtb[k * 512 + d];
    float h[16] = {};
    float p[16];
#pragma unroll
    for (int n = 0; n < 16; ++n) p[n] = 1.0f;
    for (int ll = 0; ll < 32; ++ll) {
        size_t off = (size_t)tokx(bk, chunk * 32 + ll) * 512 + d;
        float da = softplus_f(dts[off] + bias);
        float du = da * xsb[off];
#pragma unroll
        for (int n = 0; n < 16; ++n) {
            float a = __expf(da * An[n]);
            h[n] = fmaf(h[n], a, du * Bl[ll][n]);
            p[n] *= a;
        }
    }
    size_t pb = ((size_t)(bk * 32 + chunk) * 16) * 512 + d;
#pragma unroll
    for (int n = 0; n < 16; ++n) { P[pb + n * 512] = p[n]; Q[pb + n * 512] = h[n]; }
}

// phase B: serial combine over 32 chunks, parallel over (bk, n) -> 128 blocks
__global__ __launch_bounds__(512) void scanB_kernel(const float* __restrict__ P,
        const float* __restrict__ Q, float* __restrict__ Hst) {
    int bk = blockIdx.x >> 4;
    int n  = blockIdx.x & 15;
    int d  = threadIdx.x;
    float h = 0.0f;
    for (int chunk = 0; chunk < 32; ++chunk) {
        size_t base = ((size_t)((bk * 32 + chunk) * 16 + n)) * 512 + d;
        Hst[base] = h;
        h = fmaf(P[base], h, Q[base]);
    }
}

// phase C: replay with correct h_start, y = h.C + u*D -> ys (scan-position order)
__global__ __launch_bounds__(256) void scanC_kernel(const float* __restrict__ dts,
        const float* __restrict__ xsb, const float* __restrict__ xdbl,
        const float* __restrict__ A_logs, const float* __restrict__ dtb,
        const float* __restrict__ Hst, const float* __restrict__ Ds,
        float* __restrict__ ys) {
    int half = blockIdx.x & 1;
    int chunk = (blockIdx.x >> 1) & 31;
    int bk = blockIdx.x >> 6;
    int k = bk & 3;
    int d = half * 256 + threadIdx.x;
    __shared__ float BC[32][32];             // [ll][0:16]=B, [16:32]=C
    for (int s = threadIdx.x; s < 32 * 32; s += 256) {
        int ll = s >> 5, n = s & 31;
        BC[ll][n] = xdbl[(size_t)tokx(bk, chunk * 32 + ll) * 64 + 32 + n];
    }
    __syncthreads();
    float An[16];
#pragma unroll
    for (int n = 0; n < 16; ++n) An[n] = -__expf(A_logs[(size_t)(k * 512 + d) * 16 + n]);
    float bias = dtb[k * 512 + d];
    float h[16];
    size_t hb = ((size_t)(bk * 32 + chunk) * 16) * 512 + d;
#pragma unroll
    for (int n = 0; n < 16; ++n) h[n] = Hst[hb + n * 512];
    float Dv = Ds[k * 512 + d];
    for (int ll = 0; ll < 32; ++ll) {
        int l = chunk * 32 + ll;
        size_t off = (size_t)tokx(bk, l) * 512 + d;
        float da = softplus_f(dts[off] + bias);
        float u = xsb[off];
        float du = da * u;
        float y = 0.0f;
#pragma unroll
        for (int n = 0; n < 16; ++n) {
            float a = __expf(da * An[n]);
            h[n] = fmaf(h[n], a, du * BC[ll][n]);
            y = fmaf(h[n], BC[ll][16 + n], y);
        }
        ys[((size_t)bk * 1024 + l) * 512 + d] = fmaf(u, Dv, y);
    }
}

// ---------- merge fwd/bwd scans IN-PLACE into xz x-half ----------
__global__ __launch_bounds__(256) void merge_kernel(const float* __restrict__ ys,
        float* __restrict__ xz) {
    int idx = blockIdx.x * 256 + threadIdx.x;   // (b,nn,l,d)
    int d = idx & 511;
    int l = (idx >> 9) & 1023;
    int nn = (idx >> 19) & 1;
    int b = idx >> 20;
    float v = ys[((size_t)(b * 4 + nn) * 1024 + l) * 512 + d]
            + ys[((size_t)(b * 4 + nn + 2) * 1024 + (1023 - l)) * 512 + d];
    size_t trow = (size_t)(b * 2 + nn) * 1024 + l;
    xz[trow * 1024 + d] = v;                    // T3 := [merged_y | z]
}

// ---------- launch ----------
extern "C" void kernel_launch(void* const* d_in, const int* in_sizes, int n_in,
                              void* d_out, int out_size, void* d_ws, size_t ws_size,
                              hipStream_t stream) {
    const float* hidden  = (const float*)d_in[0];
    const float* in_bw   = (const float*)d_in[1];
    const float* in_sw   = (const float*)d_in[2];
    const float* in_sc   = (const float*)d_in[3];
    const float* conv_w  = (const float*)d_in[4];
    const float* conv_b  = (const float*)d_in[5];
    const float* x_bw    = (const float*)d_in[6];
    const float* x_sw    = (const float*)d_in[7];
    const float* x_sc    = (const float*)d_in[8];
    const float* dt_w    = (const float*)d_in[9];
    const float* dt_bias = (const float*)d_in[10];
    const float* A_logs  = (const float*)d_in[11];
    const float* Ds      = (const float*)d_in[12];
    const float* out_bw  = (const float*)d_in[13];
    const float* out_sw  = (const float*)d_in[14];
    const float* out_sc  = (const float*)d_in[15];
    float* out = (float*)d_out;
    char* ws = (char*)d_ws;

    // layout (bytes), peak 120,127,488 (< 126.4MB proven):
    //   0          XZ   16M (kan1 out -> T3 in-place at merge)
    //  16,777,216  XSB   8M (conv out; kan1 partial XZP3 BEFORE conv; kan3 OP1 after scanC)
    //  25,165,824  XDBL  1M (4096x64, atomic; inside XZP3 span before kan2)
    //  26,214,400  DTS   8M (pre-softplus delta; kan3 partial OP2 after scanC)
    //  34,603,008  ZONE 75.5M:
    //     kan1: FEAT1 37.75M @+0, XZP1 @+37.75M, XZP2 @+54.5M
    //     kan2: FEAT2 37.75M @+0
    //     scan: YS @+0 (16.8M), P @+16.8M, Q @+25.2M, HST @+33.6M
    //     kan3: FEAT3 75.5M @+0
    // 110,100,480  WCbuf 9.44M (WC1 -> refolded WC3)
    // 119,537,664  WC2  0.56M
    float* XZ    = (float*)(ws + 0);
    float* XSB   = (float*)(ws + 16777216);
    float* XDBL  = (float*)(ws + 25165824);
    float* DTS   = (float*)(ws + 26214400);
    char*  zone  = ws + 34603008;
    unsigned short* FEAT = (unsigned short*)zone;
    float* YS    = (float*)zone;
    float* P     = (float*)(zone + 16777216);
    float* Q     = (float*)(zone + 25165824);
    float* HST   = (float*)(zone + 33554432);
    float* XZP1  = (float*)(zone + 37748736);
    float* XZP2  = (float*)(zone + 54525952);
    float* XZP3  = (float*)(ws + 16777216);   // 16M over XSB+XDBL+DTS head (dead pre-conv)
    float* OP1   = (float*)(ws + 16777216);   // over dead XSB
    float* OP2   = (float*)(ws + 26214400);   // over dead DTS
    unsigned short* WCbuf = (unsigned short*)(ws + 110100480);
    unsigned short* WC2   = (unsigned short*)(ws + 119537664);

    // fold weights for kan1, kan2
    wc8_kernel<<<256, 256, 0, stream>>>(in_bw, in_sw, in_sc, WCbuf, 1024 * 512);
    wc8_kernel<<<16, 256, 0, stream>>>(x_bw, x_sw, x_sc, WC2, 64 * 512);

    // kan1: xz = KAN(hidden)   M=4096 N=1024 K=4608, 128x128 split-K x4, grid 1024 (4/CU)
    feat8_kernel<<<1024, 256, 0, stream>>>(hidden, FEAT, 4096 * 512);
    gemm_mfma3<128, 128, false><<<dim3(32, 8, 4), 256, 0, stream>>>(
        FEAT, WCbuf, XZ, XZP1, XZP2, XZP3, 4096, 1024, 4608, 1152, 32, 8, 4);
    add4_kernel<<<4096, 256, 0, stream>>>((float4*)XZ, (const float4*)XZP1,
        (const float4*)XZP2, (const float4*)XZP3, (4096 * 1024) / 4);

    // refold WCbuf -> kan3 weights
    wc8_kernel<<<256, 256, 0, stream>>>(out_bw, out_sw, out_sc, WCbuf, 512 * 1024);

    // conv + silu (forward xs only; backward = flipped indexing downstream)
    conv_xs_kernel<<<8192, 256, 0, stream>>>(XZ, conv_w, conv_b, XSB);

    // kan2: x_dbl = KAN(xsb)  M=4096 N=64 K=4608 (fwd tokens only), split-K x8 atomic
    feat8_kernel<<<1024, 256, 0, stream>>>(XSB, FEAT, 4096 * 512);
    zero_kernel<<<256, 256, 0, stream>>>((float4*)XDBL, (4096 * 64) / 4);
    gemm_mfma3<64, 64, true><<<dim3(64, 1, 8), 256, 0, stream>>>(
        FEAT, WC2, XDBL, XDBL, XDBL, XDBL, 4096, 64, 4608, 576, 64, 1, 8);

    // dts (pre-softplus; bias+softplus folded into scans per-direction)
    dts_kernel<<<8192, 256, 0, stream>>>(XDBL, dt_w, DTS);

    // chunked selective scan, 32 chunks x 32 steps
    scanA_kernel<<<512, 256, 0, stream>>>(DTS, XSB, XDBL, A_logs, dt_bias, P, Q);
    scanB_kernel<<<128, 512, 0, stream>>>(P, Q, HST);
    scanC_kernel<<<512, 256, 0, stream>>>(DTS, XSB, XDBL, A_logs, dt_bias, HST, Ds, YS);

    // merge into XZ x-half (T3 := XZ)
    merge_kernel<<<8192, 256, 0, stream>>>(YS, XZ);

    // kan3: out = KAN(T3)   M=4096 N=512 K=9216, 128x64 split-K x3, grid 768 (3/CU)
    feat8_kernel<<<2048, 256, 0, stream>>>(XZ, FEAT, 4096 * 1024);
    gemm_mfma3<128, 64, false><<<dim3(32, 8, 3), 256, 0, stream>>>(
        FEAT, WCbuf, out, OP1, OP2, OP2, 4096, 512, 9216, 3072, 32, 8, 3);
    add3_kernel<<<2048, 256, 0, stream>>>((float4*)out, (const float4*)OP1,
        (const float4*)OP2, (4096 * 512) / 4);
}

// Round 9
// 441.035 us; speedup vs baseline: 1.1438x; 1.1438x over previous
//
#include <hip/hip_runtime.h>
#include <stdint.h>

#define DEV __device__ __forceinline__

typedef __attribute__((ext_vector_type(8))) short short8;   // 8 bf16 = 4 VGPRs
typedef __attribute__((ext_vector_type(4))) float f32x4;

// ---------- helpers ----------
DEV unsigned short f2bf(float f) {
    union { float f; uint32_t u; } v; v.f = f;
    uint32_t u = v.u;
    return (unsigned short)((u + 0x7fffu + ((u >> 16) & 1u)) >> 16);  // RNE
}
DEV float silu_f(float x) { return x / (1.0f + __expf(-x)); }
DEV float softplus_f(float x) { return (x > 20.0f) ? x : log1pf(__expf(x)); }

// token row (0..4095) in fwd-token space for direction-k position l
DEV int tokx(int bk, int l) {            // bk = b*4 + k
    int b = bk >> 2;
    int nn = bk & 1;
    int lf = (bk & 2) ? (1023 - l) : l;  // k>=2 scans the flipped sequence
    return (b * 2 + nn) * 1024 + lf;
}

// degree-3 B-spline bases on uniform grid g[j] = 0.4*(j-3) - 1, j=0..11 -> 8 bases
DEV void bspline8(float x, float* bo) {
    float b[11];
#pragma unroll
    for (int j = 0; j < 11; ++j) {
        float gj  = 0.4f * (float)(j - 3) - 1.0f;
        float gj1 = 0.4f * (float)(j - 2) - 1.0f;
        b[j] = (x >= gj && x < gj1) ? 1.0f : 0.0f;
    }
#pragma unroll
    for (int k = 1; k <= 3; ++k) {
        float inv = 1.0f / (0.4f * (float)k);
#pragma unroll
        for (int j = 0; j + k < 11; ++j) {
            float gj  = 0.4f * (float)(j - 3) - 1.0f;      // g[j]
            float gk1 = 0.4f * (float)(j + k - 2) - 1.0f;  // g[j+k+1]
            b[j] = ((x - gj) * b[j] + (gk1 - x) * b[j + 1]) * inv;
        }
    }
#pragma unroll
    for (int j = 0; j < 8; ++j) bo[j] = b[j];
}

// ---------- zero fill ----------
__global__ __launch_bounds__(256) void zero_kernel(float4* __restrict__ p, int n4) {
    int i = blockIdx.x * 256 + threadIdx.x;
    if (i < n4) p[i] = make_float4(0.f, 0.f, 0.f, 0.f);
}

// ---------- dst += s1 + s2 ----------
__global__ __launch_bounds__(256) void add3_kernel(float4* __restrict__ dst,
        const float4* __restrict__ s1, const float4* __restrict__ s2, int n4) {
    int i = blockIdx.x * 256 + threadIdx.x;
    if (i >= n4) return;
    float4 d = dst[i], a = s1[i], b = s2[i];
    d.x += a.x + b.x; d.y += a.y + b.y; d.z += a.z + b.z; d.w += a.w + b.w;
    dst[i] = d;
}

// ---------- weight fold, FEATURE-MAJOR: Wc[o, j*IN+i] (coalesced 16B stores) ----------
// j=0: base weight; j=1..8: spline weight * scaler.
__global__ __launch_bounds__(256) void wcFM_kernel(const float* __restrict__ bw,
        const float* __restrict__ sw, const float* __restrict__ sc,
        unsigned short* __restrict__ Wc, int OUT, int IN) {
    int gid = blockIdx.x * 256 + threadIdx.x;      // 8 consecutive i per thread
    int perRow = IN >> 3;
    if (gid >= OUT * perRow) return;
    int o  = gid / perRow;
    int i0 = (gid % perRow) * 8;
    const float* bwp = bw + (size_t)o * IN + i0;
    const float* scp = sc + (size_t)o * IN + i0;
    const float* swp = sw + ((size_t)o * IN + i0) * 8;
    float bwv[8], scv[8], swv[64];
    *(float4*)&bwv[0] = *(const float4*)bwp;
    *(float4*)&bwv[4] = *(const float4*)(bwp + 4);
    *(float4*)&scv[0] = *(const float4*)scp;
    *(float4*)&scv[4] = *(const float4*)(scp + 4);
#pragma unroll
    for (int q = 0; q < 16; ++q) *(float4*)&swv[q * 4] = *(const float4*)(swp + q * 4);
    unsigned short* row = Wc + (size_t)o * 9 * IN + i0;
    short8 v;
#pragma unroll
    for (int e = 0; e < 8; ++e) v[e] = f2bf(bwv[e]);
    *(short8*)row = v;                                  // j = 0 plane
#pragma unroll
    for (int j = 1; j <= 8; ++j) {
#pragma unroll
        for (int e = 0; e < 8; ++e) v[e] = f2bf(swv[e * 8 + (j - 1)] * scv[e]);
        *(short8*)&row[(size_t)j * IN] = v;             // j plane, coalesced
    }
}

// ---------- feature expansion, FEATURE-MAJOR: F[t, j*IN+i] (coalesced) ----------
__global__ __launch_bounds__(256) void featFM_kernel(const float* __restrict__ X,
        unsigned short* __restrict__ F, int ntok, int IN) {
    int gid = blockIdx.x * 256 + threadIdx.x;
    int perRow = IN >> 3;
    if (gid >= ntok * perRow) return;
    int t  = gid / perRow;
    int i0 = (gid % perRow) * 8;
    const float* xp = X + (size_t)t * IN + i0;
    float xv[8];
    *(float4*)&xv[0] = *(const float4*)xp;
    *(float4*)&xv[4] = *(const float4*)(xp + 4);
    float bases[8][8];
    short8 v;
#pragma unroll
    for (int e = 0; e < 8; ++e) {
        v[e] = f2bf(silu_f(xv[e]));
        bspline8(xv[e], bases[e]);
    }
    unsigned short* row = F + (size_t)t * 9 * IN + i0;
    *(short8*)row = v;                                  // j = 0: silu
#pragma unroll
    for (int j = 1; j <= 8; ++j) {
#pragma unroll
        for (int e = 0; e < 8; ++e) v[e] = f2bf(bases[e][j - 1]);
        *(short8*)&row[(size_t)j * IN] = v;
    }
}

// ---------- MFMA GEMM, DEPTH=1 pipeline (NB=3), by-fastest XCD chunking ----------
// C[M,N] (+)= A[M,K'](bf16)*B[N,K'](bf16)^T over K-chunk bz; partial bz -> C0/C1/C2.
// 256 threads = 4 waves (2x2); per-wave tile (BM/2)x(BN/2); BK=32 (64B rows).
// LDS both-sides XOR swizzle (R5-verified: bank conflicts = 0).
// XCD remap: contiguous fid chunk per XCD; fid decoded BY-FASTEST so one XCD's
// blocks share A panels (A = the large FEAT matrix) -> A streamed ~once from HBM.
template<int BM, int BN, int DEPTH, bool ATOMIC>
__global__ __launch_bounds__(256) void gemm_mfma2(const unsigned short* __restrict__ A,
        const unsigned short* __restrict__ B, float* __restrict__ C0,
        float* __restrict__ C1, float* __restrict__ C2,
        int M, int N, int K, int klen, int gx, int gy, int gz) {
    constexpr int NB  = DEPTH + 2;
    constexpr int FRM = BM / 32;
    constexpr int FRN = BN / 32;
    constexpr int GLA = (BM * 64) / 4096;
    constexpr int GLB = (BN * 64) / 4096;
    constexpr int GL  = GLA + GLB;
    constexpr int LDA = BM * 32;
    constexpr int LDB = BN * 32;
    __shared__ unsigned short As[NB * LDA];
    __shared__ unsigned short Bs[NB * LDB];

    const int nwg = gx * gy * gz;
    int fid = (blockIdx.z * gy + blockIdx.y) * gx + blockIdx.x;
    int cpx = nwg >> 3;
    fid = (fid & 7) * cpx + (fid >> 3);      // XCD-contiguous chunks
    const int by = fid % gy;                 // by fastest: same-XCD shares bx (A panel)
    const int bx = (fid / gy) % gx;
    const int bz = fid / (gy * gx);

    const int tid = threadIdx.x;
    const int lane = tid & 63;
    const int w = tid >> 6;
    const int wr = w >> 1, wc = w & 1;
    const int bm = bx * BM, bn = by * BN;
    const int kbase = bz * klen;
    const int NT = klen / 32;
    const int frow = lane & 15;
    const int uq = ((lane >> 4) ^ ((frow >> 1) & 3)) * 8;   // swizzled k-quarter

    float* __restrict__ C = (bz == 0) ? C0 : (bz == 1) ? C1 : C2;

    f32x4 acc[FRM][FRN];
#pragma unroll
    for (int m = 0; m < FRM; ++m)
#pragma unroll
        for (int n = 0; n < FRN; ++n)
            acc[m][n] = (f32x4){0.f, 0.f, 0.f, 0.f};

    auto stage = [&](int t, int buf) {
        const int k0 = kbase + t * 32;
#pragma unroll
        for (int r = 0; r < GLA; ++r) {
            int bo = r * 4096 + tid * 16;
            int row = bo >> 6;
            int lu = ((bo >> 4) & 3) ^ ((row >> 1) & 3);
            __builtin_amdgcn_global_load_lds(
                (const __attribute__((address_space(1))) void*)((const char*)A + ((size_t)(bm + row) * K + k0) * 2 + lu * 16),
                (__attribute__((address_space(3))) void*)((char*)As + (size_t)buf * LDA * 2 + bo), 16, 0, 0);
        }
#pragma unroll
        for (int r = 0; r < GLB; ++r) {
            int bo = r * 4096 + tid * 16;
            int row = bo >> 6;
            int lu = ((bo >> 4) & 3) ^ ((row >> 1) & 3);
            __builtin_amdgcn_global_load_lds(
                (const __attribute__((address_space(1))) void*)((const char*)B + ((size_t)(bn + row) * K + k0) * 2 + lu * 16),
                (__attribute__((address_space(3))) void*)((char*)Bs + (size_t)buf * LDB * 2 + bo), 16, 0, 0);
        }
    };

    auto compute = [&](int buf) {
        const unsigned short* as = As + (size_t)buf * LDA;
        const unsigned short* bs = Bs + (size_t)buf * LDB;
        short8 af[FRM], bf[FRN];
#pragma unroll
        for (int m = 0; m < FRM; ++m)
            af[m] = *(const short8*)&as[(wr * (BM / 2) + m * 16 + frow) * 32 + uq];
#pragma unroll
        for (int n = 0; n < FRN; ++n)
            bf[n] = *(const short8*)&bs[(wc * (BN / 2) + n * 16 + frow) * 32 + uq];
#pragma unroll
        for (int m = 0; m < FRM; ++m)
#pragma unroll
            for (int n = 0; n < FRN; ++n)
                acc[m][n] = __builtin_amdgcn_mfma_f32_16x16x32_bf16(af[m], bf[n], acc[m][n], 0, 0, 0);
    };

    for (int t = 0; t < DEPTH; ++t) stage(t, t);

    int rb = 0, sb = DEPTH;
    int t = 0;
    for (; t + DEPTH < NT; ++t) {
        stage(t + DEPTH, sb);
        asm volatile("s_waitcnt vmcnt(%0)" :: "i"(DEPTH * GL) : "memory");
        asm volatile("s_barrier" ::: "memory");
        compute(rb);
        rb = (rb + 1 == NB) ? 0 : rb + 1;
        sb = (sb + 1 == NB) ? 0 : sb + 1;
    }
    for (; t < NT; ++t) {
        asm volatile("s_waitcnt vmcnt(0)" ::: "memory");
        asm volatile("s_barrier" ::: "memory");
        compute(rb);
        rb = (rb + 1 == NB) ? 0 : rb + 1;
    }

    // C/D layout: col=lane&15, row=(lane>>4)*4+reg  [m89/m91 verified]
    const int crow = (lane >> 4) * 4;
    const int ccol = lane & 15;
#pragma unroll
    for (int m = 0; m < FRM; ++m)
#pragma unroll
        for (int n = 0; n < FRN; ++n) {
            int gr = bm + wr * (BM / 2) + m * 16 + crow;
            int gc = bn + wc * (BN / 2) + n * 16 + ccol;
#pragma unroll
            for (int r = 0; r < 4; ++r) {
                if (ATOMIC) atomicAdd(&C[(size_t)(gr + r) * N + gc], acc[m][n][r]);
                else        C[(size_t)(gr + r) * N + gc] = acc[m][n][r];
            }
        }
}

// ---------- causal depthwise conv1d + SiLU -> xs forward only (b*2+nn, l, d) ----------
__global__ __launch_bounds__(256) void conv_xs_kernel(const float* __restrict__ xz,
        const float* __restrict__ cw, const float* __restrict__ cb,
        float* __restrict__ xsb) {
    int idx = blockIdx.x * 256 + threadIdx.x;     // (bn, l, d)
    int d = idx & 511;
    int l = (idx >> 9) & 1023;
    int bn = idx >> 19;                           // 0..3 = b*2+nn
    const float* xcol = xz + (size_t)(bn * 1024) * 1024 + d;
    float acc = cb[d];
#pragma unroll
    for (int h = 0; h < 4; ++h) {
        int ls = l - 3 + h;
        float xv = (ls >= 0) ? xcol[(size_t)ls * 1024] : 0.0f;
        acc = fmaf(cw[d * 4 + h], xv, acc);
    }
    xsb[((size_t)bn * 1024 + l) * 512 + d] = silu_f(acc);
}

// ---------- dts = xdbl[:, :32] @ dt_w^T  (no bias/softplus; 4096 fwd tokens) ----------
__global__ __launch_bounds__(256) void dts_kernel(const float* __restrict__ xdbl,
        const float* __restrict__ dtw, float* __restrict__ dts) {
    int t = blockIdx.x >> 1;                 // token 0..4095
    int half = blockIdx.x & 1;
    int d = half * 256 + threadIdx.x;
    __shared__ float dtv[32];
    if (threadIdx.x < 32) dtv[threadIdx.x] = xdbl[(size_t)t * 64 + threadIdx.x];
    __syncthreads();
    const float* w = dtw + (size_t)d * 32;
    float acc = 0.0f;
#pragma unroll
    for (int r = 0; r < 32; r += 4) {
        float4 wv = *(const float4*)(w + r);
        acc = fmaf(dtv[r], wv.x, acc);
        acc = fmaf(dtv[r + 1], wv.y, acc);
        acc = fmaf(dtv[r + 2], wv.z, acc);
        acc = fmaf(dtv[r + 3], wv.w, acc);
    }
    dts[(size_t)t * 512 + d] = acc;
}

// ---------- chunked selective scan: 32 chunks x 32 steps, delta inline ----------
// phase A: per (bk,chunk,d): P = prod a, Q = h_end with h0=0
__global__ __launch_bounds__(256) void scanA_kernel(const float* __restrict__ dts,
        const float* __restrict__ xsb, const float* __restrict__ xdbl,
        const float* __restrict__ A_logs, const float* __restrict__ dtb,
        float* __restrict__ P, float* __restrict__ Q) {
    int half = blockIdx.x & 1;
    int chunk = (blockIdx.x >> 1) & 31;
    int bk = blockIdx.x >> 6;                // 0..7 = b*4+k
    int k = bk & 3;
    int d = half * 256 + threadIdx.x;
    __shared__ float Bl[32][16];
    for (int s = threadIdx.x; s < 32 * 16; s += 256) {
        int ll = s >> 4, n = s & 15;
        Bl[ll][n] = xdbl[(size_t)tokx(bk, chunk * 32 + ll) * 64 + 32 + n];
    }
    __syncthreads();
    float An[16];
#pragma unroll
    for (int n = 0; n < 16; ++n) An[n] = -__expf(A_logs[(size_t)(k * 512 + d) * 16 + n]);
    float bias = dtb[k * 512 + d];
    float h[16] = {};
    float p[16];
#pragma unroll
    for (int n = 0; n < 16; ++n) p[n] = 1.0f;
    for (int ll = 0; ll < 32; ++ll) {
        size_t off = (size_t)tokx(bk, chunk * 32 + ll) * 512 + d;
        float da = softplus_f(dts[off] + bias);
        float du = da * xsb[off];
#pragma unroll
        for (int n = 0; n < 16; ++n) {
            float a = __expf(da * An[n]);
            h[n] = fmaf(h[n], a, du * Bl[ll][n]);
            p[n] *= a;
        }
    }
    size_t pb = ((size_t)(bk * 32 + chunk) * 16) * 512 + d;
#pragma unroll
    for (int n = 0; n < 16; ++n) { P[pb + n * 512] = p[n]; Q[pb + n * 512] = h[n]; }
}

// phase B: serial combine over 32 chunks, parallel over (bk, n) -> 128 blocks
__global__ __launch_bounds__(512) void scanB_kernel(const float* __restrict__ P,
        const float* __restrict__ Q, float* __restrict__ Hst) {
    int bk = blockIdx.x >> 4;
    int n  = blockIdx.x & 15;
    int d  = threadIdx.x;
    float h = 0.0f;
    for (int chunk = 0; chunk < 32; ++chunk) {
        size_t base = ((size_t)((bk * 32 + chunk) * 16 + n)) * 512 + d;
        Hst[base] = h;
        h = fmaf(P[base], h, Q[base]);
    }
}

// phase C: replay with correct h_start, y = h.C + u*D -> ys (scan-position order)
__global__ __launch_bounds__(256) void scanC_kernel(const float* __restrict__ dts,
        const float* __restrict__ xsb, const float* __restrict__ xdbl,
        const float* __restrict__ A_logs, const float* __restrict__ dtb,
        const float* __restrict__ Hst, const float* __restrict__ Ds,
        float* __restrict__ ys) {
    int half = blockIdx.x & 1;
    int chunk = (blockIdx.x >> 1) & 31;
    int bk = blockIdx.x >> 6;
    int k = bk & 3;
    int d = half * 256 + threadIdx.x;
    __shared__ float BC[32][32];             // [ll][0:16]=B, [16:32]=C
    for (int s = threadIdx.x; s < 32 * 32; s += 256) {
        int ll = s >> 5, n = s & 31;
        BC[ll][n] = xdbl[(size_t)tokx(bk, chunk * 32 + ll) * 64 + 32 + n];
    }
    __syncthreads();
    float An[16];
#pragma unroll
    for (int n = 0; n < 16; ++n) An[n] = -__expf(A_logs[(size_t)(k * 512 + d) * 16 + n]);
    float bias = dtb[k * 512 + d];
    float h[16];
    size_t hb = ((size_t)(bk * 32 + chunk) * 16) * 512 + d;
#pragma unroll
    for (int n = 0; n < 16; ++n) h[n] = Hst[hb + n * 512];
    float Dv = Ds[k * 512 + d];
    for (int ll = 0; ll < 32; ++ll) {
        int l = chunk * 32 + ll;
        size_t off = (size_t)tokx(bk, l) * 512 + d;
        float da = softplus_f(dts[off] + bias);
        float u = xsb[off];
        float du = da * u;
        float y = 0.0f;
#pragma unroll
        for (int n = 0; n < 16; ++n) {
            float a = __expf(da * An[n]);
            h[n] = fmaf(h[n], a, du * BC[ll][n]);
            y = fmaf(h[n], BC[ll][16 + n], y);
        }
        ys[((size_t)bk * 1024 + l) * 512 + d] = fmaf(u, Dv, y);
    }
}

// ---------- merge fwd/bwd scans IN-PLACE into xz x-half ----------
__global__ __launch_bounds__(256) void merge_kernel(const float* __restrict__ ys,
        float* __restrict__ xz) {
    int idx = blockIdx.x * 256 + threadIdx.x;   // (b,nn,l,d)
    int d = idx & 511;
    int l = (idx >> 9) & 1023;
    int nn = (idx >> 19) & 1;
    int b = idx >> 20;
    float v = ys[((size_t)(b * 4 + nn) * 1024 + l) * 512 + d]
            + ys[((size_t)(b * 4 + nn + 2) * 1024 + (1023 - l)) * 512 + d];
    size_t trow = (size_t)(b * 2 + nn) * 1024 + l;
    xz[trow * 1024 + d] = v;                    // T3 := [merged_y | z]
}

// ---------- launch ----------
extern "C" void kernel_launch(void* const* d_in, const int* in_sizes, int n_in,
                              void* d_out, int out_size, void* d_ws, size_t ws_size,
                              hipStream_t stream) {
    const float* hidden  = (const float*)d_in[0];
    const float* in_bw   = (const float*)d_in[1];
    const float* in_sw   = (const float*)d_in[2];
    const float* in_sc   = (const float*)d_in[3];
    const float* conv_w  = (const float*)d_in[4];
    const float* conv_b  = (const float*)d_in[5];
    const float* x_bw    = (const float*)d_in[6];
    const float* x_sw    = (const float*)d_in[7];
    const float* x_sc    = (const float*)d_in[8];
    const float* dt_w    = (const float*)d_in[9];
    const float* dt_bias = (const float*)d_in[10];
    const float* A_logs  = (const float*)d_in[11];
    const float* Ds      = (const float*)d_in[12];
    const float* out_bw  = (const float*)d_in[13];
    const float* out_sw  = (const float*)d_in[14];
    const float* out_sc  = (const float*)d_in[15];
    float* out = (float*)d_out;
    char* ws = (char*)d_ws;

    // layout (bytes), peak 120,127,488 (< 126.4MB proven):
    //   0          XZ   16M (kan1 out -> T3 in-place at merge)
    //  16,777,216  XSB   8M (conv out; kan3 partial OP1 after scanC)
    //  25,165,824  XDBL  1M (4096x64, atomic)
    //  26,214,400  DTS   8M (pre-softplus delta; kan3 partial OP2 after scanC)
    //  34,603,008  ZONE 75.5M:
    //     kan1: FEAT1 37.75M @+0, XZP1 @+37.75M, XZP2 @+54.5M
    //     kan2: FEAT2 37.75M @+0
    //     scan: YS @+0 (16.8M), P @+16.8M, Q @+25.2M, HST @+33.6M
    //     kan3: FEAT3 75.5M @+0
    // 110,100,480  WCbuf 9.44M (WC1 -> refolded WC3)
    // 119,537,664  WC2  0.56M
    float* XZ    = (float*)(ws + 0);
    float* XSB   = (float*)(ws + 16777216);
    float* XDBL  = (float*)(ws + 25165824);
    float* DTS   = (float*)(ws + 26214400);
    char*  zone  = ws + 34603008;
    unsigned short* FEAT = (unsigned short*)zone;
    float* YS    = (float*)zone;
    float* P     = (float*)(zone + 16777216);
    float* Q     = (float*)(zone + 25165824);
    float* HST   = (float*)(zone + 33554432);
    float* XZP1  = (float*)(zone + 37748736);
    float* XZP2  = (float*)(zone + 54525952);
    float* OP1   = (float*)(ws + 16777216);   // over dead XSB
    float* OP2   = (float*)(ws + 26214400);   // over dead DTS
    unsigned short* WCbuf = (unsigned short*)(ws + 110100480);
    unsigned short* WC2   = (unsigned short*)(ws + 119537664);

    // fold weights for kan1, kan2 (feature-major layout)
    wcFM_kernel<<<256, 256, 0, stream>>>(in_bw, in_sw, in_sc, WCbuf, 1024, 512);
    wcFM_kernel<<<16, 256, 0, stream>>>(x_bw, x_sw, x_sc, WC2, 64, 512);

    // kan1: xz = KAN(hidden)   M=4096 N=1024 K=4608, 128x128 split-K x3, grid 768
    featFM_kernel<<<1024, 256, 0, stream>>>(hidden, FEAT, 4096, 512);
    gemm_mfma2<128, 128, 1, false><<<dim3(32, 8, 3), 256, 0, stream>>>(
        FEAT, WCbuf, XZ, XZP1, XZP2, 4096, 1024, 4608, 1536, 32, 8, 3);
    add3_kernel<<<4096, 256, 0, stream>>>((float4*)XZ, (const float4*)XZP1, (const float4*)XZP2, (4096 * 1024) / 4);

    // refold WCbuf -> kan3 weights
    wcFM_kernel<<<256, 256, 0, stream>>>(out_bw, out_sw, out_sc, WCbuf, 512, 1024);

    // conv + silu (forward xs only; backward = flipped indexing downstream)
    conv_xs_kernel<<<8192, 256, 0, stream>>>(XZ, conv_w, conv_b, XSB);

    // kan2: x_dbl = KAN(xsb)  M=4096 N=64 K=4608 (fwd tokens only), split-K x8, grid 512
    featFM_kernel<<<1024, 256, 0, stream>>>(XSB, FEAT, 4096, 512);
    zero_kernel<<<256, 256, 0, stream>>>((float4*)XDBL, (4096 * 64) / 4);
    gemm_mfma2<64, 64, 1, true><<<dim3(64, 1, 8), 256, 0, stream>>>(
        FEAT, WC2, XDBL, XDBL, XDBL, 4096, 64, 4608, 576, 64, 1, 8);

    // dts (pre-softplus; bias+softplus folded into scans per-direction)
    dts_kernel<<<8192, 256, 0, stream>>>(XDBL, dt_w, DTS);

    // chunked selective scan, 32 chunks x 32 steps
    scanA_kernel<<<512, 256, 0, stream>>>(DTS, XSB, XDBL, A_logs, dt_bias, P, Q);
    scanB_kernel<<<128, 512, 0, stream>>>(P, Q, HST);
    scanC_kernel<<<512, 256, 0, stream>>>(DTS, XSB, XDBL, A_logs, dt_bias, HST, Ds, YS);

    // merge into XZ x-half (T3 := XZ)
    merge_kernel<<<8192, 256, 0, stream>>>(YS, XZ);

    // kan3: out = KAN(T3)   M=4096 N=512 K=9216, 128x64 split-K x3, grid 768
    featFM_kernel<<<2048, 256, 0, stream>>>(XZ, FEAT, 4096, 1024);
    gemm_mfma2<128, 64, 1, false><<<dim3(32, 8, 3), 256, 0, stream>>>(
        FEAT, WCbuf, out, OP1, OP2, 4096, 512, 9216, 3072, 32, 8, 3);
    add3_kernel<<<2048, 256, 0, stream>>>((float4*)out, (const float4*)OP1,
        (const float4*)OP2, (4096 * 512) / 4);
}